// Round 8
// baseline (620.038 us; speedup 1.0000x reference)
//
#include <hip/hip_runtime.h>

#define EPS 1e-5f

// ===========================================================================
// ONE persistent kernel, grid EXACTLY 1024 (= 4 blocks/CU x 256 CU, enforced
// by __launch_bounds__(256,4) + 17KB LDS -> all blocks co-resident).
//   Phase A: gemm1 partials  part[ksi][g][c], 128 row-tiles(16) x 8 k-slices
//   (device barrier)
//   Phase B: per-2-row tile: reduce 8 partials + ba1 + LN + relu; geo-MLP +
//            LN + relu; gemm2 (K=384 wave-split); LN; wc1-half proj -> aa/cc
//   (device barrier)
//   Phase C: pairwise logits, 16x16 tile per block
// Device barrier: monotonic ticket counter in __device__ globals (zeroed at
// module load; each launch adds exactly gridDim (1024) per counter, so
// target = (ticket & ~1023) + 1024 is correct on every launch/replay).
// __threadfence() release/acquire gives cross-XCD visibility (per-XCD L2s
// are not coherent).
// ws layout (float offsets): part @ 0 (16 MB), aa @ 4980736, cc @ 5111808.
// Attention branch of the reference is dead code (attn_out unused) — skipped.
// ===========================================================================

__device__ unsigned g_bar0, g_bar1;   // zero-init at module load, monotonic

__device__ __forceinline__ void gbar(unsigned* ctr)
{
    __syncthreads();
    __threadfence();                                   // release (L2 writeback)
    if (threadIdx.x == 0) {
        unsigned ticket = atomicAdd(ctr, 1u);          // device scope
        unsigned target = (ticket & ~1023u) + 1024u;
        while ((int)(__hip_atomic_load(ctr, __ATOMIC_RELAXED,
                                       __HIP_MEMORY_SCOPE_AGENT) - target) < 0)
            __builtin_amdgcn_s_sleep(2);
    }
    __syncthreads();
    __threadfence();                                   // acquire (invalidate)
}

__global__ __launch_bounds__(256, 4) void k_fused(
    const float* __restrict__ tracks, const float* __restrict__ dets,
    const float* __restrict__ wa1, const float* __restrict__ ba1,
    const float* __restrict__ gla, const float* __restrict__ bla,
    const float* __restrict__ wa2, const float* __restrict__ ba2,
    const float* __restrict__ wg1, const float* __restrict__ bg1,
    const float* __restrict__ glg, const float* __restrict__ blg,
    const float* __restrict__ wg2, const float* __restrict__ bg2,
    const float* __restrict__ gf,  const float* __restrict__ bf,
    const float* __restrict__ wc1, const float* __restrict__ bc1,
    const float* __restrict__ wc2, const float* __restrict__ bc2,
    float* __restrict__ part, float* __restrict__ aa, float* __restrict__ cc,
    float* __restrict__ out)
{
    __shared__ __align__(16) float smem[4224];   // 16.9 KB, overlaid per phase
    __shared__ float red[4][2][2];
    __shared__ float geo_s[2][4];

    const int blk = blockIdx.x;
    const int tid = threadIdx.x;
    const int w = tid >> 6, lane = tid & 63;

    // ---------------- Phase A: gemm1 partials ----------------
    {
        float* xs = smem;                      // [f][r] 128x16
        const int rt  = blk >> 3;
        const int ksi = blk & 7;
        const int g0  = rt * 16;
        const int side = g0 >> 10, b = (g0 >> 8) & 3, n0 = g0 & 255;
        const float* xb = (side ? dets : tracks) + (size_t)b * (1028 * 256);
        const int k0 = ksi * 128;
        const int c0 = lane * 4;

        for (int t = tid; t < 512; t += 256) {
            int f = t >> 2, r4 = (t & 3) << 2;
            *(float4*)(xs + f * 16 + r4) =
                *(const float4*)(xb + (size_t)(k0 + f) * 256 + n0 + r4);
        }
        __syncthreads();

        float acc[4][4];
#pragma unroll
        for (int i = 0; i < 4; ++i)
#pragma unroll
            for (int j = 0; j < 4; ++j) acc[i][j] = 0.f;

        const float* wptr = wa1 + (size_t)k0 * 256 + c0;
        float4 wb[2][4];
#pragma unroll
        for (int j = 0; j < 4; ++j)
            wb[0][j] = *(const float4*)(wptr + (size_t)j * 256);

#pragma unroll
        for (int bb = 0; bb < 32; ++bb) {          // 32 batches x 4 k
            const int cur = bb & 1, nxt = cur ^ 1;
            if (bb < 31) {
#pragma unroll
                for (int j = 0; j < 4; ++j)
                    wb[nxt][j] =
                        *(const float4*)(wptr + (size_t)((bb + 1) * 4 + j) * 256);
            }
#pragma unroll
            for (int j = 0; j < 4; ++j) {
                const int f = bb * 4 + j;
                float4 xv = *(const float4*)(xs + f * 16 + w * 4);  // uniform
                float4 wv = wb[cur][j];
                acc[0][0] = fmaf(xv.x, wv.x, acc[0][0]);
                acc[0][1] = fmaf(xv.x, wv.y, acc[0][1]);
                acc[0][2] = fmaf(xv.x, wv.z, acc[0][2]);
                acc[0][3] = fmaf(xv.x, wv.w, acc[0][3]);
                acc[1][0] = fmaf(xv.y, wv.x, acc[1][0]);
                acc[1][1] = fmaf(xv.y, wv.y, acc[1][1]);
                acc[1][2] = fmaf(xv.y, wv.z, acc[1][2]);
                acc[1][3] = fmaf(xv.y, wv.w, acc[1][3]);
                acc[2][0] = fmaf(xv.z, wv.x, acc[2][0]);
                acc[2][1] = fmaf(xv.z, wv.y, acc[2][1]);
                acc[2][2] = fmaf(xv.z, wv.z, acc[2][2]);
                acc[2][3] = fmaf(xv.z, wv.w, acc[2][3]);
                acc[3][0] = fmaf(xv.w, wv.x, acc[3][0]);
                acc[3][1] = fmaf(xv.w, wv.y, acc[3][1]);
                acc[3][2] = fmaf(xv.w, wv.z, acc[3][2]);
                acc[3][3] = fmaf(xv.w, wv.w, acc[3][3]);
            }
        }
        float* pb = part + ((size_t)ksi * 2048 + g0 + w * 4) * 256 + c0;
#pragma unroll
        for (int i = 0; i < 4; ++i)
            *(float4*)(pb + (size_t)i * 256) =
                make_float4(acc[i][0], acc[i][1], acc[i][2], acc[i][3]);
    }

    gbar(&g_bar0);

    // ---------------- Phase B: fused tail, 2-row tiles ----------------
    {
        float* h1e  = smem;                    // [384][2]
        float* psum = smem + 768;              // [4][2][256]
        float* emb  = smem + 2816;             // [256][2]
        float* ps2  = smem + 3328;             // [2][2][128]
        const int g0 = blk * 2;
        const int side = g0 >> 10, b = (g0 >> 8) & 3, n0 = g0 & 255;
        const float* xb = (side ? dets : tracks) + (size_t)b * (1028 * 256);
        const int c = tid;

        if (tid < 8)
            geo_s[tid >> 2][tid & 3] =
                xb[(size_t)(1024 + (tid & 3)) * 256 + n0 + (tid >> 2)];

        // reduce 8 K-partials + ba1
        float h[2];
#pragma unroll
        for (int i = 0; i < 2; ++i) {
            float s = ba1[c];
#pragma unroll
            for (int s8 = 0; s8 < 8; ++s8)
                s += part[((size_t)s8 * 2048 + g0 + i) * 256 + c];
            h[i] = s;
        }
#pragma unroll
        for (int i = 0; i < 2; ++i) {
            float s = h[i], s2 = h[i] * h[i];
#pragma unroll
            for (int off = 32; off >= 1; off >>= 1) {
                s  += __shfl_xor(s,  off, 64);
                s2 += __shfl_xor(s2, off, 64);
            }
            if (lane == 0) { red[w][i][0] = s; red[w][i][1] = s2; }
        }
        __syncthreads();
        {
            float gv = gla[c], bv = bla[c];
            float o0, o1;
            {
                float s  = red[0][0][0] + red[1][0][0] + red[2][0][0] + red[3][0][0];
                float s2 = red[0][0][1] + red[1][0][1] + red[2][0][1] + red[3][0][1];
                float m = s * (1.f / 256.f), var = s2 * (1.f / 256.f) - m * m;
                o0 = fmaxf((h[0] - m) * rsqrtf(var + EPS) * gv + bv, 0.f);
            }
            {
                float s  = red[0][1][0] + red[1][1][0] + red[2][1][0] + red[3][1][0];
                float s2 = red[0][1][1] + red[1][1][1] + red[2][1][1] + red[3][1][1];
                float m = s * (1.f / 256.f), var = s2 * (1.f / 256.f) - m * m;
                o1 = fmaxf((h[1] - m) * rsqrtf(var + EPS) * gv + bv, 0.f);
            }
            *(float2*)(h1e + c * 2) = make_float2(o0, o1);
        }
        __syncthreads();    // red consumed before geo phase reuses it

        // geo MLP + LN(128) + relu -> h1e[256..384)
        float gh[2];
        if (tid < 128) {
            const int j = tid;
#pragma unroll
            for (int i = 0; i < 2; ++i) {
                float s = bg1[j];
#pragma unroll
                for (int f = 0; f < 4; ++f)
                    s = fmaf(geo_s[i][f], wg1[f * 128 + j], s);
                gh[i] = s;
            }
#pragma unroll
            for (int i = 0; i < 2; ++i) {
                float s = gh[i], s2 = gh[i] * gh[i];
#pragma unroll
                for (int off = 32; off >= 1; off >>= 1) {
                    s  += __shfl_xor(s,  off, 64);
                    s2 += __shfl_xor(s2, off, 64);
                }
                if (lane == 0) { red[w][i][0] = s; red[w][i][1] = s2; }
            }
        }
        __syncthreads();
        if (tid < 128) {
            const int j = tid;
            float gv = glg[j], bv = blg[j];
            float o0, o1;
            {
                float s  = red[0][0][0] + red[1][0][0];
                float s2 = red[0][0][1] + red[1][0][1];
                float m = s * (1.f / 128.f), var = s2 * (1.f / 128.f) - m * m;
                o0 = fmaxf((gh[0] - m) * rsqrtf(var + EPS) * gv + bv, 0.f);
            }
            {
                float s  = red[0][1][0] + red[1][1][0];
                float s2 = red[0][1][1] + red[1][1][1];
                float m = s * (1.f / 128.f), var = s2 * (1.f / 128.f) - m * m;
                o1 = fmaxf((gh[1] - m) * rsqrtf(var + EPS) * gv + bv, 0.f);
            }
            *(float2*)(h1e + (256 + j) * 2) = make_float2(o0, o1);
        }
        __syncthreads();    // h1e complete

        // gemm2, K-split by wave: wa2 [w*64,+64), wg2 [w*32,+32); lane->4 cols
        const int c0 = lane * 4;
        float acc[2][4];
#pragma unroll
        for (int i = 0; i < 2; ++i)
#pragma unroll
            for (int j = 0; j < 4; ++j) acc[i][j] = 0.f;
        {
            const int ka = w * 64;
#pragma unroll 4
            for (int k = 0; k < 64; ++k) {
                float2 xv = *(const float2*)(h1e + (ka + k) * 2);   // uniform
                float4 wv = *(const float4*)(wa2 + (size_t)(ka + k) * 256 + c0);
                acc[0][0] = fmaf(xv.x, wv.x, acc[0][0]);
                acc[0][1] = fmaf(xv.x, wv.y, acc[0][1]);
                acc[0][2] = fmaf(xv.x, wv.z, acc[0][2]);
                acc[0][3] = fmaf(xv.x, wv.w, acc[0][3]);
                acc[1][0] = fmaf(xv.y, wv.x, acc[1][0]);
                acc[1][1] = fmaf(xv.y, wv.y, acc[1][1]);
                acc[1][2] = fmaf(xv.y, wv.z, acc[1][2]);
                acc[1][3] = fmaf(xv.y, wv.w, acc[1][3]);
            }
            const int kg = w * 32;
#pragma unroll 4
            for (int k = 0; k < 32; ++k) {
                float2 xv = *(const float2*)(h1e + (256 + kg + k) * 2);
                float4 wv = *(const float4*)(wg2 + (size_t)(kg + k) * 256 + c0);
                acc[0][0] = fmaf(xv.x, wv.x, acc[0][0]);
                acc[0][1] = fmaf(xv.x, wv.y, acc[0][1]);
                acc[0][2] = fmaf(xv.x, wv.z, acc[0][2]);
                acc[0][3] = fmaf(xv.x, wv.w, acc[0][3]);
                acc[1][0] = fmaf(xv.y, wv.x, acc[1][0]);
                acc[1][1] = fmaf(xv.y, wv.y, acc[1][1]);
                acc[1][2] = fmaf(xv.y, wv.z, acc[1][2]);
                acc[1][3] = fmaf(xv.y, wv.w, acc[1][3]);
            }
        }
#pragma unroll
        for (int i = 0; i < 2; ++i)
            *(float4*)(psum + (w * 2 + i) * 256 + c0) =
                make_float4(acc[i][0], acc[i][1], acc[i][2], acc[i][3]);
        __syncthreads();

        // combine wave partials + ba2+bg2, LN(gf,bf) -> emb
        float h2[2];
#pragma unroll
        for (int i = 0; i < 2; ++i) {
            float s = ba2[c] + bg2[c];
#pragma unroll
            for (int w4 = 0; w4 < 4; ++w4)
                s += psum[(w4 * 2 + i) * 256 + c];
            h2[i] = s;
        }
#pragma unroll
        for (int i = 0; i < 2; ++i) {
            float s = h2[i], s2 = h2[i] * h2[i];
#pragma unroll
            for (int off = 32; off >= 1; off >>= 1) {
                s  += __shfl_xor(s,  off, 64);
                s2 += __shfl_xor(s2, off, 64);
            }
            if (lane == 0) { red[w][i][0] = s; red[w][i][1] = s2; }
        }
        __syncthreads();
        {
            float gv = gf[c], bv = bf[c];
            float e0, e1;
            {
                float s  = red[0][0][0] + red[1][0][0] + red[2][0][0] + red[3][0][0];
                float s2 = red[0][0][1] + red[1][0][1] + red[2][0][1] + red[3][0][1];
                float m = s * (1.f / 256.f), var = s2 * (1.f / 256.f) - m * m;
                e0 = (h2[0] - m) * rsqrtf(var + EPS) * gv + bv;
            }
            {
                float s  = red[0][1][0] + red[1][1][0] + red[2][1][0] + red[3][1][0];
                float s2 = red[0][1][1] + red[1][1][1] + red[2][1][1] + red[3][1][1];
                float m = s * (1.f / 256.f), var = s2 * (1.f / 256.f) - m * m;
                e1 = (h2[1] - m) * rsqrtf(var + EPS) * gv + bv;
            }
            *(float2*)(emb + c * 2) = make_float2(e0, e1);
        }
        __syncthreads();

        // wc1-half projection -> aa/cc rows
        const int half = tid >> 7, j = tid & 127;
        const float* wch = wc1 + (size_t)side * (256 * 128);
        float p0 = 0.f, p1 = 0.f;
#pragma unroll 4
        for (int k = 0; k < 128; ++k) {
            int kk = half * 128 + k;
            float wv = wch[(size_t)kk * 128 + j];               // coalesced
            float2 ev = *(const float2*)(emb + kk * 2);         // broadcast
            p0 = fmaf(ev.x, wv, p0);
            p1 = fmaf(ev.y, wv, p1);
        }
        ps2[(half * 2 + 0) * 128 + j] = p0;
        ps2[(half * 2 + 1) * 128 + j] = p1;
        __syncthreads();

        float* outp = (side ? cc : aa) + ((size_t)b * 256 + n0) * 128;
        {
            int i = tid >> 7, jo = tid & 127;
            outp[(size_t)i * 128 + jo] =
                ps2[i * 128 + jo] + ps2[(2 + i) * 128 + jo];
        }
    }

    gbar(&g_bar1);

    // ---------------- Phase C: pairwise logits ----------------
    {
        float4* a_s = (float4*)smem;           // [16*33]
        float4* c_s = ((float4*)smem) + 528;   // [16*33]
        const int b  = blk >> 8;
        const int n0 = ((blk >> 4) & 15) << 4;
        const int m0 = (blk & 15) << 4;

        const float4* a4  = (const float4*)(aa + ((size_t)b * 256 + n0) * 128);
        const float4* c4  = (const float4*)(cc + ((size_t)b * 256 + m0) * 128);
        const float4* b14 = (const float4*)bc1;
        for (int idx = tid; idx < 512; idx += 256) {
            int r = idx >> 5, q = idx & 31;
            float4 av = a4[r * 32 + q], bv = b14[q];
            a_s[r * 33 + q] = make_float4(av.x + bv.x, av.y + bv.y,
                                          av.z + bv.z, av.w + bv.w);
            c_s[r * 33 + q] = c4[r * 32 + q];
        }
        __syncthreads();

        const int ni = tid >> 4, mi = tid & 15;
        const float4* wp = (const float4*)wc2;
        float acc = bc2[0];
#pragma unroll 8
        for (int q = 0; q < 32; ++q) {
            float4 av = a_s[ni * 33 + q];
            float4 cv = c_s[mi * 33 + q];
            float4 wv = wp[q];                                  // uniform s_load
            acc = fmaf(fmaxf(av.x + cv.x, 0.f), wv.x, acc);
            acc = fmaf(fmaxf(av.y + cv.y, 0.f), wv.y, acc);
            acc = fmaf(fmaxf(av.z + cv.z, 0.f), wv.z, acc);
            acc = fmaf(fmaxf(av.w + cv.w, 0.f), wv.w, acc);
        }
        out[((size_t)b * 256 + n0 + ni) * 256 + m0 + mi] = acc;
    }
}

extern "C" void kernel_launch(void* const* d_in, const int* in_sizes, int n_in,
                              void* d_out, int out_size, void* d_ws, size_t ws_size,
                              hipStream_t stream)
{
    const float* tracks = (const float*)d_in[0];
    const float* dets   = (const float*)d_in[1];
    const float* wa1 = (const float*)d_in[2];
    const float* ba1 = (const float*)d_in[3];
    const float* gla = (const float*)d_in[4];
    const float* bla = (const float*)d_in[5];
    const float* wa2 = (const float*)d_in[6];
    const float* ba2 = (const float*)d_in[7];
    const float* wg1 = (const float*)d_in[8];
    const float* bg1 = (const float*)d_in[9];
    const float* glg = (const float*)d_in[10];
    const float* blg = (const float*)d_in[11];
    const float* wg2 = (const float*)d_in[12];
    const float* bg2 = (const float*)d_in[13];
    const float* gf  = (const float*)d_in[14];
    const float* bf  = (const float*)d_in[15];
    // d_in[16..23]: attention weights — dead code in reference.
    const float* wc1 = (const float*)d_in[24];
    const float* bc1 = (const float*)d_in[25];
    const float* wc2 = (const float*)d_in[26];
    const float* bc2 = (const float*)d_in[27];
    float* out = (float*)d_out;
    float* ws  = (float*)d_ws;

    float* part = ws;
    float* aa   = ws + 4980736;
    float* cc   = ws + 5111808;

    hipLaunchKernelGGL(k_fused, dim3(1024), dim3(256), 0, stream,
                       tracks, dets, wa1, ba1, gla, bla, wa2, ba2,
                       wg1, bg1, glg, blg, wg2, bg2, gf, bf,
                       wc1, bc1, wc2, bc2, part, aa, cc, out);
}

// Round 9
// 160.532 us; speedup vs baseline: 3.8624x; 3.8624x over previous
//
#include <hip/hip_runtime.h>

#define EPS 1e-5f

// ===========================================================================
// 3-kernel pipeline (round 9 = round 7 + tail prefetch + pairwise 2x blocking)
//   k_gemm1   : x @ wa1 partials, K-split 8, 32-row tiles. grid 512.
//   k_tail    : reduce+LN+relu, geo-MLP+LN+relu, gemm2 (K-split by wave,
//               8-deep reg prefetch), LN, wc1 projection -> a/c. grid 512.
//   k_pairwise: relu(a+c+bc1)@wc2 logits. 32x16 tiles, 2 out/thread. grid 512.
// ws layout (float offsets):
//   part @ 0       : 8 * 2048 * 256 = 4,194,304 (16 MB)
//   aout @ 4980736 : 4*256*128
//   cout @ 5111808 : 4*256*128
// Attention branch of the reference is dead code (attn_out unused) — skipped.
// Device barrier in-kernel (R8) measured 525us -> abandoned; separate
// kernel launches are the cheap global sync.
// ===========================================================================

// GEMM1 partial: part[ksi][g][c] = sum_{k in 128-slice} x[g][k] * wa1[k][c]
// grid 512 = 64 row-tiles(32 rows) x 8 k-slices. Wave owns an 8-row group
// (2 uniform ds_read_b128 per k), lane owns 4 cols (float4 weight load,
// 8-deep double-buffered register prefetch). ksi=blk&7 == XCD id -> each
// XCD's L2 serves exactly one 128KB wa1 slice.
__global__ __launch_bounds__(256, 2) void k_gemm1(
    const float* __restrict__ tracks, const float* __restrict__ dets,
    const float* __restrict__ wa1, float* __restrict__ part)
{
    __shared__ __align__(16) float xs[128 * 32];   // [f][r] 16KB
    const int blk = blockIdx.x;
    const int rt  = blk >> 3;
    const int ksi = blk & 7;
    const int g0  = rt * 32;
    const int side = g0 >> 10, b = (g0 >> 8) & 3, n0 = g0 & 255;
    const float* xb = (side ? dets : tracks) + (size_t)b * (1028 * 256);
    const int k0 = ksi * 128;
    const int tid = threadIdx.x;
    const int w   = tid >> 6;          // wave -> rows w*8 .. w*8+7
    const int c0  = (tid & 63) * 4;    // lane -> 4 output cols

    for (int t = tid; t < 1024; t += 256) {
        int f = t >> 3, r4 = (t & 7) << 2;
        *(float4*)(xs + f * 32 + r4) =
            *(const float4*)(xb + (size_t)(k0 + f) * 256 + n0 + r4);
    }
    __syncthreads();

    float acc[8][4];
#pragma unroll
    for (int i = 0; i < 8; ++i)
#pragma unroll
        for (int j = 0; j < 4; ++j) acc[i][j] = 0.f;

    const float* wptr = wa1 + (size_t)k0 * 256 + c0;
    float4 wb[2][8];
#pragma unroll
    for (int j = 0; j < 8; ++j)
        wb[0][j] = *(const float4*)(wptr + (size_t)j * 256);

#pragma unroll
    for (int bb = 0; bb < 16; ++bb) {          // 16 batches x 8 k
        const int cur = bb & 1, nxt = cur ^ 1;
        if (bb < 15) {
#pragma unroll
            for (int j = 0; j < 8; ++j)
                wb[nxt][j] =
                    *(const float4*)(wptr + (size_t)((bb + 1) * 8 + j) * 256);
        }
#pragma unroll
        for (int j = 0; j < 8; ++j) {
            const int f = bb * 8 + j;
            float4 x0 = *(const float4*)(xs + f * 32 + w * 8);      // uniform
            float4 x1 = *(const float4*)(xs + f * 32 + w * 8 + 4);  // uniform
            float4 wv = wb[cur][j];
            float xv[8] = {x0.x, x0.y, x0.z, x0.w, x1.x, x1.y, x1.z, x1.w};
#pragma unroll
            for (int i = 0; i < 8; ++i) {
                acc[i][0] = fmaf(xv[i], wv.x, acc[i][0]);
                acc[i][1] = fmaf(xv[i], wv.y, acc[i][1]);
                acc[i][2] = fmaf(xv[i], wv.z, acc[i][2]);
                acc[i][3] = fmaf(xv[i], wv.w, acc[i][3]);
            }
        }
    }
    float* pb = part + ((size_t)ksi * 2048 + g0 + w * 8) * 256 + c0;
#pragma unroll
    for (int i = 0; i < 8; ++i)
        *(float4*)(pb + (size_t)i * 256) =
            make_float4(acc[i][0], acc[i][1], acc[i][2], acc[i][3]);
}

// Fused tail: per 4-row tile — reduce 8 partials + ba1, LN(256), relu;
// geo-MLP + LN(128) + relu; gemm2 K=384 split across waves (reg-prefetched);
// LN(gf,bf); wc1-half projection -> a/c rows.  grid 512.
__global__ __launch_bounds__(256, 2) void k_tail(
    const float* __restrict__ tracks, const float* __restrict__ dets,
    const float* __restrict__ part,
    const float* __restrict__ ba1, const float* __restrict__ gla,
    const float* __restrict__ bla,
    const float* __restrict__ wg1, const float* __restrict__ bg1,
    const float* __restrict__ glg, const float* __restrict__ blg,
    const float* __restrict__ wa2, const float* __restrict__ ba2,
    const float* __restrict__ wg2, const float* __restrict__ bg2,
    const float* __restrict__ gf,  const float* __restrict__ bf,
    const float* __restrict__ wc1,
    float* __restrict__ aout, float* __restrict__ cout)
{
    __shared__ __align__(16) float h1e[384 * 4];    // [k][row] 6KB
    __shared__ __align__(16) float psum[16 * 256];  // [w*4+row][c] 16KB
    __shared__ __align__(16) float emb[256 * 4];    // [k][row] 4KB
    __shared__ float ps2[2][4][128];
    __shared__ float red[4][4][2];
    __shared__ float geo_s[4][4];

    const int blk = blockIdx.x;
    const int g0 = blk * 4;
    const int side = g0 >> 10, b = (g0 >> 8) & 3, n0 = g0 & 255;
    const float* xb = (side ? dets : tracks) + (size_t)b * (1028 * 256);
    const int tid = threadIdx.x, w = tid >> 6, lane = tid & 63, c = tid;

    if (tid < 16)
        geo_s[tid >> 2][tid & 3] =
            xb[(size_t)(1024 + (tid & 3)) * 256 + n0 + (tid >> 2)];

    // ---- 1: reduce 8 K-partials + ba1, LN, relu ----
    float h[4];
#pragma unroll
    for (int i = 0; i < 4; ++i) {
        float s = ba1[c];
#pragma unroll
        for (int s8 = 0; s8 < 8; ++s8)
            s += part[((size_t)s8 * 2048 + g0 + i) * 256 + c];
        h[i] = s;
    }
#pragma unroll
    for (int i = 0; i < 4; ++i) {
        float s = h[i], s2 = h[i] * h[i];
#pragma unroll
        for (int off = 32; off >= 1; off >>= 1) {
            s  += __shfl_xor(s,  off, 64);
            s2 += __shfl_xor(s2, off, 64);
        }
        if (lane == 0) { red[w][i][0] = s; red[w][i][1] = s2; }
    }
    __syncthreads();
    {
        float gv = gla[c], bv = bla[c];
#pragma unroll
        for (int i = 0; i < 4; ++i) {
            float s  = red[0][i][0] + red[1][i][0] + red[2][i][0] + red[3][i][0];
            float s2 = red[0][i][1] + red[1][i][1] + red[2][i][1] + red[3][i][1];
            float m   = s * (1.f / 256.f);
            float var = s2 * (1.f / 256.f) - m * m;
            h1e[c * 4 + i] =
                fmaxf((h[i] - m) * rsqrtf(var + EPS) * gv + bv, 0.f);
        }
    }
    __syncthreads();   // red consumers done

    // ---- 2: geo MLP + LN(128) + relu -> h1e[256..384) ----
    float gh[4];
    if (tid < 128) {
        const int j = tid;
#pragma unroll
        for (int i = 0; i < 4; ++i) {
            float s = bg1[j];
#pragma unroll
            for (int f = 0; f < 4; ++f)
                s = fmaf(geo_s[i][f], wg1[f * 128 + j], s);
            gh[i] = s;
        }
#pragma unroll
        for (int i = 0; i < 4; ++i) {
            float s = gh[i], s2 = gh[i] * gh[i];
#pragma unroll
            for (int off = 32; off >= 1; off >>= 1) {
                s  += __shfl_xor(s,  off, 64);
                s2 += __shfl_xor(s2, off, 64);
            }
            if (lane == 0) { red[w][i][0] = s; red[w][i][1] = s2; }
        }
    }
    __syncthreads();
    if (tid < 128) {
        const int j = tid;
        float gv = glg[j], bv = blg[j];
#pragma unroll
        for (int i = 0; i < 4; ++i) {
            float s  = red[0][i][0] + red[1][i][0];
            float s2 = red[0][i][1] + red[1][i][1];
            float m   = s * (1.f / 128.f);
            float var = s2 * (1.f / 128.f) - m * m;
            h1e[(256 + j) * 4 + i] =
                fmaxf((gh[i] - m) * rsqrtf(var + EPS) * gv + bv, 0.f);
        }
    }
    __syncthreads();   // h1e complete

    // ---- 3: gemm2, K-split by wave (wa2 [w*64,+64), wg2 [w*32,+32)),
    //         8-deep double-buffered weight prefetch ----
    const int c0 = lane * 4;
    float acc[4][4];
#pragma unroll
    for (int i = 0; i < 4; ++i)
#pragma unroll
        for (int j = 0; j < 4; ++j) acc[i][j] = 0.f;

    {
        const int ka = w * 64;
        const float* wpa = wa2 + (size_t)ka * 256 + c0;
        float4 wb[2][4];
#pragma unroll
        for (int j = 0; j < 4; ++j)
            wb[0][j] = *(const float4*)(wpa + (size_t)j * 256);
#pragma unroll
        for (int bb = 0; bb < 16; ++bb) {              // 16 batches x 4 k
            const int cur = bb & 1, nxt = cur ^ 1;
            if (bb < 15) {
#pragma unroll
                for (int j = 0; j < 4; ++j)
                    wb[nxt][j] =
                        *(const float4*)(wpa + (size_t)((bb + 1) * 4 + j) * 256);
            }
#pragma unroll
            for (int j = 0; j < 4; ++j) {
                const int k = bb * 4 + j;
                float4 xv = *(const float4*)(h1e + (ka + k) * 4);   // uniform
                float4 wv = wb[cur][j];
#pragma unroll
                for (int i = 0; i < 4; ++i) {
                    float x = (&xv.x)[i];
                    acc[i][0] = fmaf(x, wv.x, acc[i][0]);
                    acc[i][1] = fmaf(x, wv.y, acc[i][1]);
                    acc[i][2] = fmaf(x, wv.z, acc[i][2]);
                    acc[i][3] = fmaf(x, wv.w, acc[i][3]);
                }
            }
        }
        const int kg = w * 32;
        const float* wpg = wg2 + (size_t)kg * 256 + c0;
#pragma unroll
        for (int j = 0; j < 4; ++j)
            wb[0][j] = *(const float4*)(wpg + (size_t)j * 256);
#pragma unroll
        for (int bb = 0; bb < 8; ++bb) {               // 8 batches x 4 k
            const int cur = bb & 1, nxt = cur ^ 1;
            if (bb < 7) {
#pragma unroll
                for (int j = 0; j < 4; ++j)
                    wb[nxt][j] =
                        *(const float4*)(wpg + (size_t)((bb + 1) * 4 + j) * 256);
            }
#pragma unroll
            for (int j = 0; j < 4; ++j) {
                const int k = bb * 4 + j;
                float4 xv = *(const float4*)(h1e + (256 + kg + k) * 4);
                float4 wv = wb[cur][j];
#pragma unroll
                for (int i = 0; i < 4; ++i) {
                    float x = (&xv.x)[i];
                    acc[i][0] = fmaf(x, wv.x, acc[i][0]);
                    acc[i][1] = fmaf(x, wv.y, acc[i][1]);
                    acc[i][2] = fmaf(x, wv.z, acc[i][2]);
                    acc[i][3] = fmaf(x, wv.w, acc[i][3]);
                }
            }
        }
    }
#pragma unroll
    for (int i = 0; i < 4; ++i)
        *(float4*)(psum + (w * 4 + i) * 256 + c0) =
            make_float4(acc[i][0], acc[i][1], acc[i][2], acc[i][3]);
    __syncthreads();

    // ---- 4: combine wave partials + ba2+bg2, LN(gf,bf) -> emb ----
    float h2[4];
#pragma unroll
    for (int i = 0; i < 4; ++i) {
        float s = ba2[c] + bg2[c];
#pragma unroll
        for (int w4 = 0; w4 < 4; ++w4)
            s += psum[(w4 * 4 + i) * 256 + c];
        h2[i] = s;
    }
#pragma unroll
    for (int i = 0; i < 4; ++i) {
        float s = h2[i], s2 = h2[i] * h2[i];
#pragma unroll
        for (int off = 32; off >= 1; off >>= 1) {
            s  += __shfl_xor(s,  off, 64);
            s2 += __shfl_xor(s2, off, 64);
        }
        if (lane == 0) { red[w][i][0] = s; red[w][i][1] = s2; }
    }
    __syncthreads();
    {
        float gv = gf[c], bv = bf[c];
#pragma unroll
        for (int i = 0; i < 4; ++i) {
            float s  = red[0][i][0] + red[1][i][0] + red[2][i][0] + red[3][i][0];
            float s2 = red[0][i][1] + red[1][i][1] + red[2][i][1] + red[3][i][1];
            float m   = s * (1.f / 256.f);
            float var = s2 * (1.f / 256.f) - m * m;
            emb[c * 4 + i] = (h2[i] - m) * rsqrtf(var + EPS) * gv + bv;
        }
    }
    __syncthreads();

    // ---- 5: projection with this side's wc1 half -> a/c rows ----
    const int half = tid >> 7, j = tid & 127;
    const float* wch = wc1 + (size_t)side * (256 * 128);
    float a4[4] = {0.f, 0.f, 0.f, 0.f};
#pragma unroll 4
    for (int k = 0; k < 128; ++k) {
        int kk = half * 128 + k;
        float wv = wch[(size_t)kk * 128 + j];                 // coalesced
        float4 ev = *(const float4*)(emb + kk * 4);           // broadcast
        a4[0] = fmaf(ev.x, wv, a4[0]); a4[1] = fmaf(ev.y, wv, a4[1]);
        a4[2] = fmaf(ev.z, wv, a4[2]); a4[3] = fmaf(ev.w, wv, a4[3]);
    }
#pragma unroll
    for (int i = 0; i < 4; ++i) ps2[half][i][j] = a4[i];
    __syncthreads();

    float* outp = (side ? cout : aout) + ((size_t)b * 256 + n0) * 128;
    for (int idx = tid; idx < 512; idx += 256) {
        int i = idx >> 7, jo = idx & 127;
        outp[(size_t)i * 128 + jo] = ps2[0][i][jo] + ps2[1][i][jo];
    }
}

// Pairwise: logits[b,n,m] = sum_j relu(a[n,j]+c[m,j]+bc1[j])*wc2[j] + bc2
// grid 512 (2 blk/CU), 32x16 tile, 2 outputs/thread (rows ni, ni+16).
__global__ __launch_bounds__(256) void k_pairwise(
    const float* __restrict__ a, const float* __restrict__ cmat,
    const float* __restrict__ bc1, const float* __restrict__ wc2,
    const float* __restrict__ bc2, float* __restrict__ out)
{
    __shared__ float4 a_s[32 * 33];
    __shared__ float4 c_s[16 * 33];
    const int blk = blockIdx.x;              // 4b x 8nt x 16mt = 512
    const int b   = blk >> 7;
    const int rem = blk & 127;
    const int n0  = (rem >> 4) << 5;
    const int m0  = (rem & 15) << 4;
    const int tid = threadIdx.x;

    const float4* a4  = (const float4*)(a    + ((size_t)b * 256 + n0) * 128);
    const float4* c4  = (const float4*)(cmat + ((size_t)b * 256 + m0) * 128);
    const float4* b14 = (const float4*)bc1;
    for (int idx = tid; idx < 1024; idx += 256) {   // 32 rows x 32 q
        int r = idx >> 5, q = idx & 31;
        float4 av = a4[r * 32 + q], bv = b14[q];
        a_s[r * 33 + q] = make_float4(av.x + bv.x, av.y + bv.y,
                                      av.z + bv.z, av.w + bv.w);
    }
    for (int idx = tid; idx < 512; idx += 256) {    // 16 rows x 32 q
        int r = idx >> 5, q = idx & 31;
        c_s[r * 33 + q] = c4[r * 32 + q];
    }
    __syncthreads();

    const int ni = tid >> 4, mi = tid & 15;
    const float4* wp = (const float4*)wc2;
    float s0 = 0.f, s1 = 0.f;
#pragma unroll 4
    for (int q = 0; q < 32; ++q) {
        float4 av0 = a_s[ni * 33 + q];
        float4 av1 = a_s[(ni + 16) * 33 + q];
        float4 cv  = c_s[mi * 33 + q];
        float4 wv  = wp[q];                                   // uniform s_load
        s0 = fmaf(fmaxf(av0.x + cv.x, 0.f), wv.x, s0);
        s0 = fmaf(fmaxf(av0.y + cv.y, 0.f), wv.y, s0);
        s0 = fmaf(fmaxf(av0.z + cv.z, 0.f), wv.z, s0);
        s0 = fmaf(fmaxf(av0.w + cv.w, 0.f), wv.w, s0);
        s1 = fmaf(fmaxf(av1.x + cv.x, 0.f), wv.x, s1);
        s1 = fmaf(fmaxf(av1.y + cv.y, 0.f), wv.y, s1);
        s1 = fmaf(fmaxf(av1.z + cv.z, 0.f), wv.z, s1);
        s1 = fmaf(fmaxf(av1.w + cv.w, 0.f), wv.w, s1);
    }
    const float b2 = bc2[0];
    float* ob = out + ((size_t)b * 256 + n0) * 256 + m0 + mi;
    ob[(size_t)ni * 256]        = s0 + b2;
    ob[(size_t)(ni + 16) * 256] = s1 + b2;
}

extern "C" void kernel_launch(void* const* d_in, const int* in_sizes, int n_in,
                              void* d_out, int out_size, void* d_ws, size_t ws_size,
                              hipStream_t stream)
{
    const float* tracks = (const float*)d_in[0];
    const float* dets   = (const float*)d_in[1];
    const float* wa1 = (const float*)d_in[2];
    const float* ba1 = (const float*)d_in[3];
    const float* gla = (const float*)d_in[4];
    const float* bla = (const float*)d_in[5];
    const float* wa2 = (const float*)d_in[6];
    const float* ba2 = (const float*)d_in[7];
    const float* wg1 = (const float*)d_in[8];
    const float* bg1 = (const float*)d_in[9];
    const float* glg = (const float*)d_in[10];
    const float* blg = (const float*)d_in[11];
    const float* wg2 = (const float*)d_in[12];
    const float* bg2 = (const float*)d_in[13];
    const float* gf  = (const float*)d_in[14];
    const float* bf  = (const float*)d_in[15];
    // d_in[16..23]: attention weights — dead code in reference.
    const float* wc1 = (const float*)d_in[24];
    const float* bc1 = (const float*)d_in[25];
    const float* wc2 = (const float*)d_in[26];
    const float* bc2 = (const float*)d_in[27];
    float* out = (float*)d_out;
    float* ws  = (float*)d_ws;

    float* part = ws;
    float* aa   = ws + 4980736;
    float* cc   = ws + 5111808;

    hipLaunchKernelGGL(k_gemm1, dim3(512), dim3(256), 0, stream,
                       tracks, dets, wa1, part);
    hipLaunchKernelGGL(k_tail, dim3(512), dim3(256), 0, stream,
                       tracks, dets, part, ba1, gla, bla,
                       wg1, bg1, glg, blg, wa2, ba2, wg2, bg2,
                       gf, bf, wc1, aa, cc);
    hipLaunchKernelGGL(k_pairwise, dim3(512), dim3(256), 0, stream,
                       aa, cc, bc1, wc2, bc2, out);
}